// Round 2
// baseline (747.257 us; speedup 1.0000x reference)
//
#include <hip/hip_runtime.h>

#define NN 50000
#define NE 600000
#define D  128

// ---------------------------------------------------------------- degree
__global__ __launch_bounds__(256) void deg_kernel(const int* __restrict__ dst,
                                                  float* __restrict__ deg) {
    int e = blockIdx.x * 256 + threadIdx.x;
    if (e < NE) atomicAdd(&deg[dst[e]], 1.0f);
}

__global__ __launch_bounds__(256) void dinv_kernel(float* __restrict__ deg) {
    int i = blockIdx.x * 256 + threadIdx.x;
    if (i < NN) {
        float dg = deg[i];
        deg[i] = rsqrtf(dg > 1.0f ? dg : 1.0f);   // clip(deg,1)^-0.5
    }
}

// ------------------------------------------------- edge scatter (atomics)
// agg[dst, d] += feat[src, d] * dinv[src]; one thread per (edge, d).
__global__ __launch_bounds__(256) void scatter_kernel(const float* __restrict__ feat,
                                                      const int* __restrict__ src,
                                                      const int* __restrict__ dst,
                                                      const float* __restrict__ dinv,
                                                      float* __restrict__ agg) {
    unsigned idx = blockIdx.x * 256u + threadIdx.x;   // < 76.8M (NE*D)
    unsigned e = idx >> 7;
    unsigned d = idx & 127u;
    if (e < NE) {
        int s = src[e];
        int t = dst[e];
        float w = dinv[s];
        atomicAdd(&agg[(size_t)t * D + d], feat[(size_t)s * D + d] * w);
    }
}

// ---------------------------------------------- feat1 = feat0 - agg*dinv*diag1
// written into d_out (aliased as featA staging buffer)
__global__ __launch_bounds__(256) void feat1_kernel(const float* __restrict__ feat0,
                                                    const float* __restrict__ agg,
                                                    const float* __restrict__ dinv,
                                                    const float* __restrict__ diag,
                                                    float* __restrict__ featA) {
    unsigned idx = blockIdx.x * 256u + threadIdx.x;
    if (idx < (unsigned)(NN * D)) {
        unsigned i = idx >> 7, d = idx & 127u;
        featA[idx] = feat0[idx] - agg[idx] * dinv[i] * diag[D + d];
    }
}

// ------------------------------------------------------- GEMM + epilogue
// h[i,d] = sum_j (0.5*feat0[i,j]*diag0[j]) * W[d,j] + b[d]
//          - 0.5*featA[i,d] - 0.5*agg2[i,d]*dinv[i]*diag2[d]
//   (h = h0 + th1*feat1 + th2*feat2, th=(0.5,-1,0.5), feat2 folded in)
#define GR 32
__global__ __launch_bounds__(256) void gemm_final_kernel(const float* __restrict__ feat0,
                                                         const float* __restrict__ agg,
                                                         const float* __restrict__ dinv,
                                                         const float* __restrict__ diag,
                                                         const float* __restrict__ W,
                                                         const float* __restrict__ b,
                                                         float* __restrict__ out) {
    __shared__ float x_lds[GR][D];        // 16 KB
    __shared__ float wt_lds[64][133];     // 34 KB, wt_lds[jl][d] = W[d][c*64+jl]

    const int t = threadIdx.x;
    const int d = t & 127;
    const int rsub = t >> 7;              // 0 or 1
    const int row0 = blockIdx.x * GR;

    // stage x = 0.5 * feat0 * diag0 for 32 rows (coalesced)
    #pragma unroll
    for (int i = 0; i < GR * D / 256; ++i) {   // 16 iters
        int lin = i * 256 + t;
        int r = lin >> 7, j = lin & 127;
        int gr = row0 + r;
        float v = (gr < NN) ? feat0[(size_t)gr * D + j] : 0.0f;
        x_lds[r][j] = 0.5f * v * diag[j];
    }

    float acc[GR / 2];
    #pragma unroll
    for (int rr = 0; rr < GR / 2; ++rr) acc[rr] = 0.0f;

    for (int c = 0; c < 2; ++c) {
        __syncthreads();
        // stage W chunk: wt_lds[jl][dg] = W[dg][c*64+jl]  (coalesced global read)
        #pragma unroll
        for (int i = 0; i < 64 * D / 256; ++i) {   // 32 iters
            int lin = i * 256 + t;
            int dg = lin >> 6;
            int jl = lin & 63;
            wt_lds[jl][dg] = W[(size_t)dg * D + c * 64 + jl];
        }
        __syncthreads();

        #pragma unroll 2
        for (int jl4 = 0; jl4 < 16; ++jl4) {
            const int j = c * 64 + jl4 * 4;
            const float w0 = wt_lds[jl4 * 4 + 0][d];
            const float w1 = wt_lds[jl4 * 4 + 1][d];
            const float w2 = wt_lds[jl4 * 4 + 2][d];
            const float w3 = wt_lds[jl4 * 4 + 3][d];
            #pragma unroll
            for (int rr = 0; rr < GR / 2; ++rr) {
                const float4 xv = *(const float4*)&x_lds[rsub + 2 * rr][j];
                acc[rr] += xv.x * w0 + xv.y * w1 + xv.z * w2 + xv.w * w3;
            }
        }
    }

    const float bd  = b[d];
    const float dg2 = diag[2 * D + d];
    #pragma unroll
    for (int rr = 0; rr < GR / 2; ++rr) {
        int gr = row0 + rsub + 2 * rr;
        if (gr < NN) {
            size_t idx = (size_t)gr * D + d;
            float f1 = out[idx];       // featA staged here by feat1_kernel
            float ag = agg[idx];
            out[idx] = acc[rr] + bd - 0.5f * f1 - 0.5f * ag * dinv[gr] * dg2;
        }
    }
}

// ----------------------------------------------------------------- launch
extern "C" void kernel_launch(void* const* d_in, const int* in_sizes, int n_in,
                              void* d_out, int out_size, void* d_ws, size_t ws_size,
                              hipStream_t stream) {
    const float* feat = (const float*)d_in[0];
    const int*   eidx = (const int*)d_in[1];
    const float* diag = (const float*)d_in[2];
    const float* W    = (const float*)d_in[3];
    const float* b    = (const float*)d_in[4];
    float* out = (float*)d_out;

    const int* src = eidx;            // edge_index[0]
    const int* dst = eidx + NE;       // edge_index[1]

    float* agg = (float*)d_ws;         // NN*D floats = 25.6 MB
    float* deg = agg + (size_t)NN * D; // NN floats (becomes dinv in place)

    // zero scratch (ws is poisoned 0xAA before every launch)
    hipMemsetAsync(deg, 0, (size_t)NN * sizeof(float), stream);
    hipMemsetAsync(agg, 0, (size_t)NN * D * sizeof(float), stream);

    deg_kernel<<<(NE + 255) / 256, 256, 0, stream>>>(dst, deg);
    dinv_kernel<<<(NN + 255) / 256, 256, 0, stream>>>(deg);

    const int scatter_blocks = (NE * D) / 256;   // 300000

    // round 1: agg = scatter(feat0 * dinv)
    scatter_kernel<<<scatter_blocks, 256, 0, stream>>>(feat, src, dst, deg, agg);
    // feat1 -> staged in d_out
    feat1_kernel<<<(NN * D + 255) / 256, 256, 0, stream>>>(feat, agg, deg, diag, out);

    // round 2: agg = scatter(feat1 * dinv)
    hipMemsetAsync(agg, 0, (size_t)NN * D * sizeof(float), stream);
    scatter_kernel<<<scatter_blocks, 256, 0, stream>>>(out, src, dst, deg, agg);

    // GEMM + fused epilogue -> d_out
    gemm_final_kernel<<<(NN + GR - 1) / GR, 256, 0, stream>>>(feat, agg, deg, diag, W, b, out);
}

// Round 3
// 346.645 us; speedup vs baseline: 2.1557x; 2.1557x over previous
//
#include <hip/hip_runtime.h>

#define NN 50000
#define NE 600000
#define D  128
#define NBLK 196   // ceil(NN/256)

// ------------------------------------------------------------ histogram
__global__ __launch_bounds__(256) void hist_kernel(const int* __restrict__ dst,
                                                   int* __restrict__ deg_i) {
    int e = blockIdx.x * 256 + threadIdx.x;
    if (e < NE) atomicAdd(&deg_i[dst[e]], 1);
}

__global__ __launch_bounds__(256) void dinv_kernel(const int* __restrict__ deg_i,
                                                   float* __restrict__ dinvf) {
    int i = blockIdx.x * 256 + threadIdx.x;
    if (i < NN) {
        float dg = (float)deg_i[i];
        dinvf[i] = rsqrtf(dg > 1.0f ? dg : 1.0f);   // clip(deg,1)^-0.5
    }
}

// ------------------------------------------------- hierarchical scan (row_ptr)
__global__ __launch_bounds__(256) void scan1_kernel(const int* __restrict__ deg_i,
                                                    int* __restrict__ row_ptr,
                                                    int* __restrict__ partials) {
    __shared__ int sh[256];
    int i = blockIdx.x * 256 + threadIdx.x;
    sh[threadIdx.x] = (i < NN) ? deg_i[i] : 0;
    __syncthreads();
    #pragma unroll
    for (int off = 1; off < 256; off <<= 1) {
        int t = (threadIdx.x >= off) ? sh[threadIdx.x - off] : 0;
        __syncthreads();
        sh[threadIdx.x] += t;
        __syncthreads();
    }
    if (i < NN) row_ptr[i + 1] = sh[threadIdx.x];
    if (threadIdx.x == 255) partials[blockIdx.x] = sh[255];
}

__global__ __launch_bounds__(256) void scan2_kernel(int* __restrict__ partials) {
    __shared__ int sh[256];
    sh[threadIdx.x] = (threadIdx.x < NBLK) ? partials[threadIdx.x] : 0;
    __syncthreads();
    #pragma unroll
    for (int off = 1; off < 256; off <<= 1) {
        int t = (threadIdx.x >= off) ? sh[threadIdx.x - off] : 0;
        __syncthreads();
        sh[threadIdx.x] += t;
        __syncthreads();
    }
    if (threadIdx.x < NBLK) partials[threadIdx.x] = sh[threadIdx.x];
}

__global__ __launch_bounds__(256) void scan3_kernel(int* __restrict__ row_ptr,
                                                    const int* __restrict__ partials) {
    int i = blockIdx.x * 256 + threadIdx.x;
    if (i < NN) {
        int add = (blockIdx.x > 0) ? partials[blockIdx.x - 1] : 0;
        row_ptr[i + 1] += add;
    }
    if (i == 0) row_ptr[0] = 0;
}

// ------------------------------------------------------------- CSR fill
// csr[pos] = (src, dinv[src]) packed
__global__ __launch_bounds__(256) void fill_kernel(const int* __restrict__ src,
                                                   const int* __restrict__ dst,
                                                   const int* __restrict__ row_ptr,
                                                   const float* __restrict__ dinvf,
                                                   int* __restrict__ fill,
                                                   int2* __restrict__ csr) {
    int e = blockIdx.x * 256 + threadIdx.x;
    if (e < NE) {
        int t = dst[e];
        int s = src[e];
        int pos = row_ptr[t] + atomicAdd(&fill[t], 1);
        csr[pos] = make_int2(s, __float_as_int(dinvf[s]));
    }
}

// ------------------------------------------------- gather (one wave per node)
// acc[d] = sum_{e in-edges(i)} feat_in[src_e, d] * dinv[src_e]
// out[i,d] = alpha * (base[i,d] + sgn * acc[d] * dinvf[i] * diagk[d])
//   gather1: alpha=1,    sgn=-1, base=feat0,  diagk=diag1, out=feat1 (ws)
//   gather2: alpha=-0.5, sgn=+1, base=feat1,  diagk=diag2, out=d_out (rest)
template <int SGN>
__global__ __launch_bounds__(256) void gather_kernel(const float* __restrict__ feat_in,
                                                     const int2* __restrict__ csr,
                                                     const int* __restrict__ row_ptr,
                                                     const float* __restrict__ dinvf,
                                                     const float* __restrict__ diagk,
                                                     const float* __restrict__ base,
                                                     float* __restrict__ outp,
                                                     float alpha) {
    const int node = blockIdx.x * 4 + (threadIdx.x >> 6);   // grid=12500 -> 50000 waves
    const int lane = threadIdx.x & 63;
    const int e0 = row_ptr[node];
    const int e1 = row_ptr[node + 1];

    float2 acc = make_float2(0.0f, 0.0f);
    for (int bse = e0; bse < e1; bse += 64) {
        int idx = bse + lane;
        int s = 0;
        float w = 0.0f;
        if (idx < e1) {
            int2 p = csr[idx];
            s = p.x;
            w = __int_as_float(p.y);
        }
        int cnt = min(64, e1 - bse);
        for (int k = 0; k < cnt; ++k) {
            int   ss = __shfl(s, k);
            float ww = __shfl(w, k);
            const float2 fv = *(const float2*)&feat_in[(size_t)ss * D + 2 * lane];
            acc.x += fv.x * ww;
            acc.y += fv.y * ww;
        }
    }

    const size_t o = (size_t)node * D + 2 * lane;
    const float di = dinvf[node];
    const float2 bs = *(const float2*)&base[o];
    const float2 dg = *(const float2*)&diagk[2 * lane];
    float2 r;
    r.x = alpha * (bs.x + (float)SGN * acc.x * di * dg.x);
    r.y = alpha * (bs.y + (float)SGN * acc.y * di * dg.y);
    *(float2*)&outp[o] = r;
}

// ------------------------------------------------------- GEMM + epilogue
// out[i,d] = rest[i,d] + sum_j (0.5*feat0[i,j]*diag0[j]) * W[d,j] + b[d]
#define GR 32
__global__ __launch_bounds__(256) void gemm_final_kernel(const float* __restrict__ feat0,
                                                         const float* __restrict__ diag,
                                                         const float* __restrict__ W,
                                                         const float* __restrict__ b,
                                                         float* __restrict__ out) {
    __shared__ float x_lds[GR][D];        // 16 KB
    __shared__ float wt_lds[64][133];     // 34 KB, wt_lds[jl][d] = W[d][c*64+jl]

    const int t = threadIdx.x;
    const int d = t & 127;
    const int rsub = t >> 7;              // 0 or 1
    const int row0 = blockIdx.x * GR;

    #pragma unroll
    for (int i = 0; i < GR * D / 256; ++i) {   // 16 iters
        int lin = i * 256 + t;
        int r = lin >> 7, j = lin & 127;
        int gr = row0 + r;
        float v = (gr < NN) ? feat0[(size_t)gr * D + j] : 0.0f;
        x_lds[r][j] = 0.5f * v * diag[j];
    }

    float acc[GR / 2];
    #pragma unroll
    for (int rr = 0; rr < GR / 2; ++rr) acc[rr] = 0.0f;

    for (int c = 0; c < 2; ++c) {
        __syncthreads();
        #pragma unroll
        for (int i = 0; i < 64 * D / 256; ++i) {   // 32 iters
            int lin = i * 256 + t;
            int dg = lin >> 6;
            int jl = lin & 63;
            wt_lds[jl][dg] = W[(size_t)dg * D + c * 64 + jl];
        }
        __syncthreads();

        #pragma unroll 2
        for (int jl4 = 0; jl4 < 16; ++jl4) {
            const int j = c * 64 + jl4 * 4;
            const float w0 = wt_lds[jl4 * 4 + 0][d];
            const float w1 = wt_lds[jl4 * 4 + 1][d];
            const float w2 = wt_lds[jl4 * 4 + 2][d];
            const float w3 = wt_lds[jl4 * 4 + 3][d];
            #pragma unroll
            for (int rr = 0; rr < GR / 2; ++rr) {
                const float4 xv = *(const float4*)&x_lds[rsub + 2 * rr][j];
                acc[rr] += xv.x * w0 + xv.y * w1 + xv.z * w2 + xv.w * w3;
            }
        }
    }

    const float bd = b[d];
    #pragma unroll
    for (int rr = 0; rr < GR / 2; ++rr) {
        int gr = row0 + rsub + 2 * rr;
        if (gr < NN) {
            size_t idx = (size_t)gr * D + d;
            out[idx] = acc[rr] + bd + out[idx];   // out holds "rest" from gather2
        }
    }
}

// ----------------------------------------------------------------- launch
extern "C" void kernel_launch(void* const* d_in, const int* in_sizes, int n_in,
                              void* d_out, int out_size, void* d_ws, size_t ws_size,
                              hipStream_t stream) {
    const float* feat = (const float*)d_in[0];
    const int*   eidx = (const int*)d_in[1];
    const float* diag = (const float*)d_in[2];
    const float* W    = (const float*)d_in[3];
    const float* b    = (const float*)d_in[4];
    float* out = (float*)d_out;

    const int* src = eidx;            // edge_index[0]
    const int* dst = eidx + NE;       // edge_index[1]

    // ---- workspace layout (~31.2 MB) ----
    float* feat1    = (float*)d_ws;                 // NN*D = 25.6 MB
    float* dinvf    = feat1 + (size_t)NN * D;       // NN
    int*   deg_i    = (int*)(dinvf + NN);           // NN
    int*   row_ptr  = deg_i + NN;                   // NN+2 (padded even)
    int*   fill     = row_ptr + NN + 2;             // NN
    int*   partials = fill + NN;                    // 256
    int2*  csr      = (int2*)(partials + 256);      // NE * 8B = 4.8 MB

    hipMemsetAsync(deg_i, 0, (size_t)NN * sizeof(int), stream);
    hipMemsetAsync(fill,  0, (size_t)NN * sizeof(int), stream);

    hist_kernel<<<(NE + 255) / 256, 256, 0, stream>>>(dst, deg_i);
    dinv_kernel<<<NBLK, 256, 0, stream>>>(deg_i, dinvf);

    scan1_kernel<<<NBLK, 256, 0, stream>>>(deg_i, row_ptr, partials);
    scan2_kernel<<<1, 256, 0, stream>>>(partials);
    scan3_kernel<<<NBLK, 256, 0, stream>>>(row_ptr, partials);

    fill_kernel<<<(NE + 255) / 256, 256, 0, stream>>>(src, dst, row_ptr, dinvf, fill, csr);

    // round 1: feat1 = feat0 - agg1*dinv*diag1   (agg never materialized)
    gather_kernel<-1><<<NN / 4, 256, 0, stream>>>(feat, csr, row_ptr, dinvf,
                                                  diag + D, feat, feat1, 1.0f);
    // round 2: rest = -0.5*feat1 - 0.5*agg2*dinv*diag2  -> d_out
    gather_kernel<+1><<<NN / 4, 256, 0, stream>>>(feat1, csr, row_ptr, dinvf,
                                                  diag + 2 * D, feat1, out, -0.5f);

    // out += 0.5*(feat0*diag0) @ W^T + b
    gemm_final_kernel<<<(NN + GR - 1) / GR, 256, 0, stream>>>(feat, diag, W, b, out);
}

// Round 4
// 291.556 us; speedup vs baseline: 2.5630x; 1.1889x over previous
//
#include <hip/hip_runtime.h>

#define NN 50000
#define NE 600000
#define D  128
#define NBLK 196   // ceil(NN/256)

typedef __attribute__((ext_vector_type(8))) short bf16x8;
typedef __attribute__((ext_vector_type(4))) float floatx4;

__device__ __forceinline__ unsigned short bf16_rne(float f) {
    union { float f; unsigned u; } v; v.f = f;
    unsigned r = v.u + 0x7FFFu + ((v.u >> 16) & 1u);
    return (unsigned short)(r >> 16);
}

// ------------------------------------------------------------ histogram
__global__ __launch_bounds__(256) void hist_kernel(const int* __restrict__ dst,
                                                   int* __restrict__ deg_i) {
    int e = blockIdx.x * 256 + threadIdx.x;
    if (e < NE) atomicAdd(&deg_i[dst[e]], 1);
}

__global__ __launch_bounds__(256) void dinv_kernel(const int* __restrict__ deg_i,
                                                   float* __restrict__ dinvf) {
    int i = blockIdx.x * 256 + threadIdx.x;
    if (i < NN) {
        float dg = (float)deg_i[i];
        dinvf[i] = rsqrtf(dg > 1.0f ? dg : 1.0f);   // clip(deg,1)^-0.5
    }
}

// ------------------------------------------------- hierarchical scan (row_ptr)
__global__ __launch_bounds__(256) void scan1_kernel(const int* __restrict__ deg_i,
                                                    int* __restrict__ row_ptr,
                                                    int* __restrict__ partials) {
    __shared__ int sh[256];
    int i = blockIdx.x * 256 + threadIdx.x;
    sh[threadIdx.x] = (i < NN) ? deg_i[i] : 0;
    __syncthreads();
    #pragma unroll
    for (int off = 1; off < 256; off <<= 1) {
        int t = (threadIdx.x >= off) ? sh[threadIdx.x - off] : 0;
        __syncthreads();
        sh[threadIdx.x] += t;
        __syncthreads();
    }
    if (i < NN) row_ptr[i + 1] = sh[threadIdx.x];
    if (threadIdx.x == 255) partials[blockIdx.x] = sh[255];
}

__global__ __launch_bounds__(256) void scan2_kernel(int* __restrict__ partials) {
    __shared__ int sh[256];
    sh[threadIdx.x] = (threadIdx.x < NBLK) ? partials[threadIdx.x] : 0;
    __syncthreads();
    #pragma unroll
    for (int off = 1; off < 256; off <<= 1) {
        int t = (threadIdx.x >= off) ? sh[threadIdx.x - off] : 0;
        __syncthreads();
        sh[threadIdx.x] += t;
        __syncthreads();
    }
    if (threadIdx.x < NBLK) partials[threadIdx.x] = sh[threadIdx.x];
}

__global__ __launch_bounds__(256) void scan3_kernel(int* __restrict__ row_ptr,
                                                    const int* __restrict__ partials) {
    int i = blockIdx.x * 256 + threadIdx.x;
    if (i < NN) {
        int add = (blockIdx.x > 0) ? partials[blockIdx.x - 1] : 0;
        row_ptr[i + 1] += add;
    }
    if (i == 0) row_ptr[0] = 0;
}

// ------------------------------------------------------------- CSR fill
__global__ __launch_bounds__(256) void fill_kernel(const int* __restrict__ src,
                                                   const int* __restrict__ dst,
                                                   const int* __restrict__ row_ptr,
                                                   const float* __restrict__ dinvf,
                                                   int* __restrict__ fill,
                                                   int2* __restrict__ csr) {
    int e = blockIdx.x * 256 + threadIdx.x;
    if (e < NE) {
        int t = dst[e];
        int s = src[e];
        int pos = row_ptr[t] + atomicAdd(&fill[t], 1);
        csr[pos] = make_int2(s, __float_as_int(dinvf[s]));
    }
}

// ------------------------------------------------- gather (one wave per node)
// acc[d] = sum_{e in-edges(i)} feat_in[src_e, d] * dinv[src_e]
// out[i,d] = alpha * (base[i,d] + sgn * acc[d] * dinvf[i] * diagk[d])
template <int SGN>
__global__ __launch_bounds__(256) void gather_kernel(const float* __restrict__ feat_in,
                                                     const int2* __restrict__ csr,
                                                     const int* __restrict__ row_ptr,
                                                     const float* __restrict__ dinvf,
                                                     const float* __restrict__ diagk,
                                                     const float* __restrict__ base,
                                                     float* __restrict__ outp,
                                                     float alpha) {
    const int node = blockIdx.x * 4 + (threadIdx.x >> 6);
    const int lane = threadIdx.x & 63;
    const int e0 = row_ptr[node];
    const int e1 = row_ptr[node + 1];

    float2 acc = make_float2(0.0f, 0.0f);
    for (int bse = e0; bse < e1; bse += 64) {
        int idx = bse + lane;
        int s = 0;
        float w = 0.0f;
        if (idx < e1) {
            int2 p = csr[idx];
            s = p.x;
            w = __int_as_float(p.y);
        }
        int cnt = min(64, e1 - bse);
        for (int k = 0; k < cnt; ++k) {
            int   ss = __shfl(s, k);
            float ww = __shfl(w, k);
            const float2 fv = *(const float2*)&feat_in[(size_t)ss * D + 2 * lane];
            acc.x += fv.x * ww;
            acc.y += fv.y * ww;
        }
    }

    const size_t o = (size_t)node * D + 2 * lane;
    const float di = dinvf[node];
    const float2 bs = *(const float2*)&base[o];
    const float2 dg = *(const float2*)&diagk[2 * lane];
    float2 r;
    r.x = alpha * (bs.x + (float)SGN * acc.x * di * dg.x);
    r.y = alpha * (bs.y + (float)SGN * acc.y * di * dg.y);
    *(float2*)&outp[o] = r;
}

// --------------------------------------------- Wb = bf16(0.5 * diag0 * W)
__global__ __launch_bounds__(256) void wprep_kernel(const float* __restrict__ W,
                                                    const float* __restrict__ diag,
                                                    unsigned short* __restrict__ Wb) {
    int idx = blockIdx.x * 256 + threadIdx.x;   // 16384 total
    int j = idx & 127;
    Wb[idx] = bf16_rne(0.5f * diag[j] * W[idx]);
}

// -------------------------------------------------- MFMA GEMM + epilogue
// out[i,d] = out[i,d](rest) + sum_j feat[i,j]*Wb[d,j] + b[d]
// One wave per 16 rows; 8 n-tiles x 4 k-chunks of mfma_f32_16x16x32_bf16.
// No LDS: A frags straight from fp32 feat (RNE->bf16), B frags from 32KB
// L2-resident Wb.
__global__ __launch_bounds__(256) void gemm_mfma_kernel(const float* __restrict__ feat,
                                                        const unsigned short* __restrict__ Wb,
                                                        const float* __restrict__ b,
                                                        float* __restrict__ out) {
    const int wv   = threadIdx.x >> 6;
    const int lane = threadIdx.x & 63;
    const int r16  = lane & 15;
    const int quad = lane >> 4;
    const int m0   = blockIdx.x * 64 + wv * 16;

    const int mrow = m0 + r16;
    const int mc   = (mrow < NN) ? mrow : (NN - 1);
    const float* arow = feat + (size_t)mc * D + quad * 8;

    bf16x8 afrag[4];
    #pragma unroll
    for (int kc = 0; kc < 4; ++kc) {
        const float4 f0 = *(const float4*)(arow + kc * 32);
        const float4 f1 = *(const float4*)(arow + kc * 32 + 4);
        bf16x8 a;
        a[0] = (short)bf16_rne(f0.x); a[1] = (short)bf16_rne(f0.y);
        a[2] = (short)bf16_rne(f0.z); a[3] = (short)bf16_rne(f0.w);
        a[4] = (short)bf16_rne(f1.x); a[5] = (short)bf16_rne(f1.y);
        a[6] = (short)bf16_rne(f1.z); a[7] = (short)bf16_rne(f1.w);
        afrag[kc] = a;
    }

    floatx4 acc[8];
    #pragma unroll
    for (int nt = 0; nt < 8; ++nt) acc[nt] = (floatx4)(0.0f);

    #pragma unroll
    for (int nt = 0; nt < 8; ++nt) {
        const unsigned short* brow = Wb + (size_t)(nt * 16 + r16) * D + quad * 8;
        #pragma unroll
        for (int kc = 0; kc < 4; ++kc) {
            const bf16x8 bfrag = *(const bf16x8*)(brow + kc * 32);
            acc[nt] = __builtin_amdgcn_mfma_f32_16x16x32_bf16(afrag[kc], bfrag, acc[nt], 0, 0, 0);
        }
    }

    // epilogue: C/D layout col=lane&15 (d), row=quad*4+reg (i)
    #pragma unroll
    for (int nt = 0; nt < 8; ++nt) {
        const int d = nt * 16 + r16;
        const float bd = b[d];
        #pragma unroll
        for (int r = 0; r < 4; ++r) {
            const int i = m0 + quad * 4 + r;
            if (i < NN) {
                const size_t o = (size_t)i * D + d;
                out[o] = acc[nt][r] + bd + out[o];   // out holds "rest" from gather2
            }
        }
    }
}

// ----------------------------------------------------------------- launch
extern "C" void kernel_launch(void* const* d_in, const int* in_sizes, int n_in,
                              void* d_out, int out_size, void* d_ws, size_t ws_size,
                              hipStream_t stream) {
    const float* feat = (const float*)d_in[0];
    const int*   eidx = (const int*)d_in[1];
    const float* diag = (const float*)d_in[2];
    const float* W    = (const float*)d_in[3];
    const float* b    = (const float*)d_in[4];
    float* out = (float*)d_out;

    const int* src = eidx;            // edge_index[0]
    const int* dst = eidx + NE;       // edge_index[1]

    // ---- workspace layout (~31.3 MB) ----
    float* feat1    = (float*)d_ws;                 // NN*D = 25.6 MB
    float* dinvf    = feat1 + (size_t)NN * D;       // NN
    int*   deg_i    = (int*)(dinvf + NN);           // NN
    int*   row_ptr  = deg_i + NN;                   // NN+2 (padded even)
    int*   fill     = row_ptr + NN + 2;             // NN
    int*   partials = fill + NN;                    // 256
    int2*  csr      = (int2*)(partials + 256);      // NE * 8B = 4.8 MB
    unsigned short* Wb = (unsigned short*)(csr + NE); // 128*128*2B = 32 KB

    hipMemsetAsync(deg_i, 0, (size_t)NN * sizeof(int), stream);
    hipMemsetAsync(fill,  0, (size_t)NN * sizeof(int), stream);

    hist_kernel<<<(NE + 255) / 256, 256, 0, stream>>>(dst, deg_i);
    dinv_kernel<<<NBLK, 256, 0, stream>>>(deg_i, dinvf);

    scan1_kernel<<<NBLK, 256, 0, stream>>>(deg_i, row_ptr, partials);
    scan2_kernel<<<1, 256, 0, stream>>>(partials);
    scan3_kernel<<<NBLK, 256, 0, stream>>>(row_ptr, partials);

    fill_kernel<<<(NE + 255) / 256, 256, 0, stream>>>(src, dst, row_ptr, dinvf, fill, csr);

    wprep_kernel<<<64, 256, 0, stream>>>(W, diag, Wb);

    // round 1: feat1 = feat0 - agg1*dinv*diag1
    gather_kernel<-1><<<NN / 4, 256, 0, stream>>>(feat, csr, row_ptr, dinvf,
                                                  diag + D, feat, feat1, 1.0f);
    // round 2: rest = -0.5*feat1 - 0.5*agg2*dinv*diag2  -> d_out
    gather_kernel<+1><<<NN / 4, 256, 0, stream>>>(feat1, csr, row_ptr, dinvf,
                                                  diag + 2 * D, feat1, out, -0.5f);

    // out += feat @ Wb^T + b   (Wb = 0.5*diag0*W in bf16)
    gemm_mfma_kernel<<<(NN + 63) / 64, 256, 0, stream>>>(feat, Wb, b, out);
}

// Round 5
// 240.410 us; speedup vs baseline: 3.1083x; 1.2127x over previous
//
#include <hip/hip_runtime.h>

#define NN 50000
#define NE 600000
#define D  128
#define NBLK 196   // ceil(NN/256)

typedef __attribute__((ext_vector_type(8))) short bf16x8;
typedef __attribute__((ext_vector_type(4))) float floatx4;

__device__ __forceinline__ unsigned short bf16_rne(float f) {
    union { float f; unsigned u; } v; v.f = f;
    unsigned r = v.u + 0x7FFFu + ((v.u >> 16) & 1u);
    return (unsigned short)(r >> 16);
}

// ------------------------------------------------------------ histogram
__global__ __launch_bounds__(256) void hist_kernel(const int* __restrict__ dst,
                                                   int* __restrict__ deg_i) {
    int e = blockIdx.x * 256 + threadIdx.x;
    if (e < NE) atomicAdd(&deg_i[dst[e]], 1);
}

// ------------------------------------------- scan1 (+ dinv folded in)
__global__ __launch_bounds__(256) void scan1_kernel(const int* __restrict__ deg_i,
                                                    int* __restrict__ row_ptr,
                                                    int* __restrict__ partials,
                                                    float* __restrict__ dinvf) {
    __shared__ int sh[256];
    int i = blockIdx.x * 256 + threadIdx.x;
    int dg = (i < NN) ? deg_i[i] : 0;
    if (i < NN) {
        float d = (float)dg;
        dinvf[i] = rsqrtf(d > 1.0f ? d : 1.0f);   // clip(deg,1)^-0.5
    }
    sh[threadIdx.x] = dg;
    __syncthreads();
    #pragma unroll
    for (int off = 1; off < 256; off <<= 1) {
        int t = (threadIdx.x >= off) ? sh[threadIdx.x - off] : 0;
        __syncthreads();
        sh[threadIdx.x] += t;
        __syncthreads();
    }
    if (i < NN) row_ptr[i + 1] = sh[threadIdx.x];
    if (threadIdx.x == 255) partials[blockIdx.x] = sh[255];
}

__global__ __launch_bounds__(256) void scan2_kernel(int* __restrict__ partials) {
    __shared__ int sh[256];
    sh[threadIdx.x] = (threadIdx.x < NBLK) ? partials[threadIdx.x] : 0;
    __syncthreads();
    #pragma unroll
    for (int off = 1; off < 256; off <<= 1) {
        int t = (threadIdx.x >= off) ? sh[threadIdx.x - off] : 0;
        __syncthreads();
        sh[threadIdx.x] += t;
        __syncthreads();
    }
    if (threadIdx.x < NBLK) partials[threadIdx.x] = sh[threadIdx.x];
}

// ------------------------------------- scan3 (+ fill-array zeroing folded in)
__global__ __launch_bounds__(256) void scan3_kernel(int* __restrict__ row_ptr,
                                                    const int* __restrict__ partials,
                                                    int* __restrict__ fillc) {
    int i = blockIdx.x * 256 + threadIdx.x;
    if (i < NN) {
        int add = (blockIdx.x > 0) ? partials[blockIdx.x - 1] : 0;
        row_ptr[i + 1] += add;
        fillc[i] = 0;
    }
    if (i == 0) row_ptr[0] = 0;
}

// ------------------------------------------------------------- CSR fill
__global__ __launch_bounds__(256) void fill_kernel(const int* __restrict__ src,
                                                   const int* __restrict__ dst,
                                                   const int* __restrict__ row_ptr,
                                                   const float* __restrict__ dinvf,
                                                   int* __restrict__ fillc,
                                                   int2* __restrict__ csr) {
    int e = blockIdx.x * 256 + threadIdx.x;
    if (e < NE) {
        int t = dst[e];
        int s = src[e];
        int pos = row_ptr[t] + atomicAdd(&fillc[t], 1);
        csr[pos] = make_int2(s, __float_as_int(dinvf[s]));
    }
}

// ---------------------------------------------------- feat -> bf16 copy
__global__ __launch_bounds__(256) void cvt_kernel(const float* __restrict__ feat,
                                                  unsigned int* __restrict__ featb) {
    int idx = blockIdx.x * 256 + threadIdx.x;   // NN*D/4 = 1.6M
    const float4 f = ((const float4*)feat)[idx];
    unsigned int lo = (unsigned)bf16_rne(f.x) | ((unsigned)bf16_rne(f.y) << 16);
    unsigned int hi = (unsigned)bf16_rne(f.z) | ((unsigned)bf16_rne(f.w) << 16);
    ((uint2*)featb)[idx] = make_uint2(lo, hi);
}

// --------------------------------------------- shared gather inner loop
// acc[2l],acc[2l+1] = sum_e feat_b[src_e, 2l..2l+1] * dinv[src_e]
__device__ __forceinline__ float2 gather_acc(const unsigned short* __restrict__ featb,
                                             const int2* __restrict__ csr,
                                             int e0, int e1, int lane) {
    float2 acc = make_float2(0.0f, 0.0f);
    for (int bse = e0; bse < e1; bse += 64) {
        int idx = bse + lane;
        int s = 0;
        float w = 0.0f;
        if (idx < e1) {
            int2 p = csr[idx];
            s = p.x;
            w = __int_as_float(p.y);
        }
        int cnt4 = (min(64, e1 - bse) + 3) & ~3;
        for (int k = 0; k < cnt4; k += 4) {
            #pragma unroll
            for (int u = 0; u < 4; ++u) {     // 4 independent shfl->load chains
                int   ss = __shfl(s, k + u);
                float ww = __shfl(w, k + u);  // 0 for padded slots
                unsigned pv = *(const unsigned*)(featb + (size_t)ss * D + 2 * lane);
                acc.x += __uint_as_float(pv << 16) * ww;
                acc.y += __uint_as_float(pv & 0xFFFF0000u) * ww;
            }
        }
    }
    return acc;
}

// round 1: feat1b = bf16( feat0(fp32) - acc * dinv * diag1 )
__global__ __launch_bounds__(256) void gather1_kernel(const unsigned short* __restrict__ featb,
                                                      const int2* __restrict__ csr,
                                                      const int* __restrict__ row_ptr,
                                                      const float* __restrict__ dinvf,
                                                      const float* __restrict__ diag,
                                                      const float* __restrict__ feat0,
                                                      unsigned int* __restrict__ feat1b) {
    const int node = blockIdx.x * 4 + (threadIdx.x >> 6);
    const int lane = threadIdx.x & 63;
    float2 acc = gather_acc(featb, csr, row_ptr[node], row_ptr[node + 1], lane);

    const size_t o2 = (size_t)node * (D / 2) + lane;
    const float di = dinvf[node];
    const float2 bs = *(const float2*)&feat0[2 * o2];
    const float2 dg = *(const float2*)&diag[D + 2 * lane];
    float rx = bs.x - acc.x * di * dg.x;
    float ry = bs.y - acc.y * di * dg.y;
    feat1b[o2] = (unsigned)bf16_rne(rx) | ((unsigned)bf16_rne(ry) << 16);
}

// round 2: rest = -0.5*(feat1 + acc * dinv * diag2)  -> d_out (fp32)
__global__ __launch_bounds__(256) void gather2_kernel(const unsigned short* __restrict__ feat1b,
                                                      const int2* __restrict__ csr,
                                                      const int* __restrict__ row_ptr,
                                                      const float* __restrict__ dinvf,
                                                      const float* __restrict__ diag,
                                                      float* __restrict__ outp) {
    const int node = blockIdx.x * 4 + (threadIdx.x >> 6);
    const int lane = threadIdx.x & 63;
    float2 acc = gather_acc(feat1b, csr, row_ptr[node], row_ptr[node + 1], lane);

    const size_t o2 = (size_t)node * (D / 2) + lane;
    const float di = dinvf[node];
    const unsigned bp = ((const unsigned*)feat1b)[o2];
    const float2 dg = *(const float2*)&diag[2 * D + 2 * lane];
    float bx = __uint_as_float(bp << 16);
    float by = __uint_as_float(bp & 0xFFFF0000u);
    float2 r;
    r.x = -0.5f * (bx + acc.x * di * dg.x);
    r.y = -0.5f * (by + acc.y * di * dg.y);
    *(float2*)&outp[2 * o2] = r;
}

// --------------------------------------------- Wb = bf16(0.5 * diag0 * W)
__global__ __launch_bounds__(256) void wprep_kernel(const float* __restrict__ W,
                                                    const float* __restrict__ diag,
                                                    unsigned short* __restrict__ Wb) {
    int idx = blockIdx.x * 256 + threadIdx.x;   // 16384 total
    int j = idx & 127;
    Wb[idx] = bf16_rne(0.5f * diag[j] * W[idx]);
}

// -------------------------------------------------- MFMA GEMM + epilogue
// out[i,d] = out[i,d](rest) + sum_j feat[i,j]*Wb[d,j] + b[d]
__global__ __launch_bounds__(256) void gemm_mfma_kernel(const float* __restrict__ feat,
                                                        const unsigned short* __restrict__ Wb,
                                                        const float* __restrict__ b,
                                                        float* __restrict__ out) {
    const int wv   = threadIdx.x >> 6;
    const int lane = threadIdx.x & 63;
    const int r16  = lane & 15;
    const int quad = lane >> 4;
    const int m0   = blockIdx.x * 64 + wv * 16;

    const int mrow = m0 + r16;
    const int mc   = (mrow < NN) ? mrow : (NN - 1);
    const float* arow = feat + (size_t)mc * D + quad * 8;

    bf16x8 afrag[4];
    #pragma unroll
    for (int kc = 0; kc < 4; ++kc) {
        const float4 f0 = *(const float4*)(arow + kc * 32);
        const float4 f1 = *(const float4*)(arow + kc * 32 + 4);
        bf16x8 a;
        a[0] = (short)bf16_rne(f0.x); a[1] = (short)bf16_rne(f0.y);
        a[2] = (short)bf16_rne(f0.z); a[3] = (short)bf16_rne(f0.w);
        a[4] = (short)bf16_rne(f1.x); a[5] = (short)bf16_rne(f1.y);
        a[6] = (short)bf16_rne(f1.z); a[7] = (short)bf16_rne(f1.w);
        afrag[kc] = a;
    }

    floatx4 acc[8];
    #pragma unroll
    for (int nt = 0; nt < 8; ++nt) acc[nt] = (floatx4)(0.0f);

    #pragma unroll
    for (int nt = 0; nt < 8; ++nt) {
        const unsigned short* brow = Wb + (size_t)(nt * 16 + r16) * D + quad * 8;
        #pragma unroll
        for (int kc = 0; kc < 4; ++kc) {
            const bf16x8 bfrag = *(const bf16x8*)(brow + kc * 32);
            acc[nt] = __builtin_amdgcn_mfma_f32_16x16x32_bf16(afrag[kc], bfrag, acc[nt], 0, 0, 0);
        }
    }

    // C/D layout: col=lane&15 (d), row=quad*4+reg (i)
    #pragma unroll
    for (int nt = 0; nt < 8; ++nt) {
        const int d = nt * 16 + r16;
        const float bd = b[d];
        #pragma unroll
        for (int r = 0; r < 4; ++r) {
            const int i = m0 + quad * 4 + r;
            if (i < NN) {
                const size_t o = (size_t)i * D + d;
                out[o] = acc[nt][r] + bd + out[o];   // out holds "rest" from gather2
            }
        }
    }
}

// ----------------------------------------------------------------- launch
extern "C" void kernel_launch(void* const* d_in, const int* in_sizes, int n_in,
                              void* d_out, int out_size, void* d_ws, size_t ws_size,
                              hipStream_t stream) {
    const float* feat = (const float*)d_in[0];
    const int*   eidx = (const int*)d_in[1];
    const float* diag = (const float*)d_in[2];
    const float* W    = (const float*)d_in[3];
    const float* b    = (const float*)d_in[4];
    float* out = (float*)d_out;

    const int* src = eidx;            // edge_index[0]
    const int* dst = eidx + NE;       // edge_index[1]

    // ---- workspace layout (~31.2 MB) ----
    unsigned short* featb  = (unsigned short*)d_ws;            // NN*D bf16 = 12.8 MB
    unsigned short* feat1b = featb + (size_t)NN * D;           // NN*D bf16 = 12.8 MB
    int2*  csr      = (int2*)(feat1b + (size_t)NN * D);        // NE*8B = 4.8 MB (8B aligned)
    float* dinvf    = (float*)(csr + NE);                      // NN
    int*   deg_i    = (int*)(dinvf + NN);                      // NN
    int*   row_ptr  = deg_i + NN;                              // NN+2
    int*   fillc    = row_ptr + NN + 2;                        // NN
    int*   partials = fillc + NN;                              // 256
    unsigned short* Wb = (unsigned short*)(partials + 256);    // 32 KB

    hipMemsetAsync(deg_i, 0, (size_t)NN * sizeof(int), stream);

    hist_kernel<<<(NE + 255) / 256, 256, 0, stream>>>(dst, deg_i);
    scan1_kernel<<<NBLK, 256, 0, stream>>>(deg_i, row_ptr, partials, dinvf);
    scan2_kernel<<<1, 256, 0, stream>>>(partials);
    scan3_kernel<<<NBLK, 256, 0, stream>>>(row_ptr, partials, fillc);
    fill_kernel<<<(NE + 255) / 256, 256, 0, stream>>>(src, dst, row_ptr, dinvf, fillc, csr);

    cvt_kernel<<<NN * D / 4 / 256, 256, 0, stream>>>(feat, (unsigned int*)featb);
    wprep_kernel<<<64, 256, 0, stream>>>(W, diag, Wb);

    // round 1: feat1b = bf16(feat0 - agg1*dinv*diag1)
    gather1_kernel<<<NN / 4, 256, 0, stream>>>(featb, csr, row_ptr, dinvf, diag,
                                               feat, (unsigned int*)feat1b);
    // round 2: rest = -0.5*feat1 - 0.5*agg2*dinv*diag2 -> d_out
    gather2_kernel<<<NN / 4, 256, 0, stream>>>(feat1b, csr, row_ptr, dinvf, diag, out);

    // out += feat @ Wb^T + b   (Wb = 0.5*diag0*W in bf16)
    gemm_mfma_kernel<<<(NN + 63) / 64, 256, 0, stream>>>(feat, Wb, b, out);
}

// Round 6
// 235.320 us; speedup vs baseline: 3.1755x; 1.0216x over previous
//
#include <hip/hip_runtime.h>

#define NN 50000
#define NE 600000
#define D  128
#define NBLK 196   // ceil(NN/256)

typedef __attribute__((ext_vector_type(8))) short bf16x8;
typedef __attribute__((ext_vector_type(4))) float floatx4;

__device__ __forceinline__ unsigned short bf16_rne(float f) {
    union { float f; unsigned u; } v; v.f = f;
    unsigned r = v.u + 0x7FFFu + ((v.u >> 16) & 1u);
    return (unsigned short)(r >> 16);
}
__device__ __forceinline__ unsigned pack2(float a, float b) {
    return (unsigned)bf16_rne(a) | ((unsigned)bf16_rne(b) << 16);
}

// ------------------------------------------------------------ histogram
__global__ __launch_bounds__(256) void hist_kernel(const int* __restrict__ dst,
                                                   int* __restrict__ deg_i) {
    int e = blockIdx.x * 256 + threadIdx.x;
    if (e < NE) atomicAdd(&deg_i[dst[e]], 1);
}

// ----------------------------------- scan1 (+ dinv & rdeg folded in)
__global__ __launch_bounds__(256) void scan1_kernel(const int* __restrict__ deg_i,
                                                    int* __restrict__ row_ptr,
                                                    int* __restrict__ partials,
                                                    float* __restrict__ dinvf,
                                                    float* __restrict__ rdegf) {
    __shared__ int sh[256];
    int i = blockIdx.x * 256 + threadIdx.x;
    int dg = (i < NN) ? deg_i[i] : 0;
    if (i < NN) {
        float d = (float)dg;
        float dc = d > 1.0f ? d : 1.0f;       // clip(deg,1)
        dinvf[i] = rsqrtf(dc);
        rdegf[i] = sqrtf(dc);                 // 1/dinv (for unscaling)
    }
    sh[threadIdx.x] = dg;
    __syncthreads();
    #pragma unroll
    for (int off = 1; off < 256; off <<= 1) {
        int t = (threadIdx.x >= off) ? sh[threadIdx.x - off] : 0;
        __syncthreads();
        sh[threadIdx.x] += t;
        __syncthreads();
    }
    if (i < NN) row_ptr[i + 1] = sh[threadIdx.x];
    if (threadIdx.x == 255) partials[blockIdx.x] = sh[255];
}

__global__ __launch_bounds__(256) void scan2_kernel(int* __restrict__ partials) {
    __shared__ int sh[256];
    sh[threadIdx.x] = (threadIdx.x < NBLK) ? partials[threadIdx.x] : 0;
    __syncthreads();
    #pragma unroll
    for (int off = 1; off < 256; off <<= 1) {
        int t = (threadIdx.x >= off) ? sh[threadIdx.x - off] : 0;
        __syncthreads();
        sh[threadIdx.x] += t;
        __syncthreads();
    }
    if (threadIdx.x < NBLK) partials[threadIdx.x] = sh[threadIdx.x];
}

// ------------------------------------- scan3 (+ fill-array zeroing folded in)
__global__ __launch_bounds__(256) void scan3_kernel(int* __restrict__ row_ptr,
                                                    const int* __restrict__ partials,
                                                    int* __restrict__ fillc) {
    int i = blockIdx.x * 256 + threadIdx.x;
    if (i < NN) {
        int add = (blockIdx.x > 0) ? partials[blockIdx.x - 1] : 0;
        row_ptr[i + 1] += add;
        fillc[i] = 0;
    }
    if (i == 0) row_ptr[0] = 0;
}

// ------------------------------------------------------- CSR fill (int-only)
__global__ __launch_bounds__(256) void fill_kernel(const int* __restrict__ src,
                                                   const int* __restrict__ dst,
                                                   const int* __restrict__ row_ptr,
                                                   int* __restrict__ fillc,
                                                   int* __restrict__ csr) {
    int e = blockIdx.x * 256 + threadIdx.x;
    if (e < NE) {
        int t = dst[e];
        int pos = row_ptr[t] + atomicAdd(&fillc[t], 1);
        csr[pos] = src[e];
    }
}

// --------------------------------------------- Wb = bf16(0.5 * diag0 * W)
__global__ __launch_bounds__(256) void wprep_kernel(const float* __restrict__ W,
                                                    const float* __restrict__ diag,
                                                    unsigned short* __restrict__ Wb) {
    int idx = blockIdx.x * 256 + threadIdx.x;   // 16384 total
    int j = idx & 127;
    Wb[idx] = bf16_rne(0.5f * diag[j] * W[idx]);
}

// ------------------------------- MFMA GEMM (h0) + featb_s byproduct
// out[i,d] = sum_j feat[i,j]*Wb[d,j] + b[d]        (fresh write)
// featb_s[i,:] = bf16(feat[i,:] * dinv[i])         (pre-scaled rows)
__global__ __launch_bounds__(256) void gemm_mfma_kernel(const float* __restrict__ feat,
                                                        const unsigned short* __restrict__ Wb,
                                                        const float* __restrict__ b,
                                                        const float* __restrict__ dinvf,
                                                        unsigned short* __restrict__ featb_s,
                                                        float* __restrict__ out) {
    const int wv   = threadIdx.x >> 6;
    const int lane = threadIdx.x & 63;
    const int r16  = lane & 15;
    const int quad = lane >> 4;
    const int m0   = blockIdx.x * 64 + wv * 16;

    const int mrow = m0 + r16;
    const int mc   = (mrow < NN) ? mrow : (NN - 1);
    const float* arow = feat + (size_t)mc * D + quad * 8;
    const float di = dinvf[mc];

    bf16x8 afrag[4];
    #pragma unroll
    for (int kc = 0; kc < 4; ++kc) {
        const float4 f0 = *(const float4*)(arow + kc * 32);
        const float4 f1 = *(const float4*)(arow + kc * 32 + 4);
        bf16x8 a;
        a[0] = (short)bf16_rne(f0.x); a[1] = (short)bf16_rne(f0.y);
        a[2] = (short)bf16_rne(f0.z); a[3] = (short)bf16_rne(f0.w);
        a[4] = (short)bf16_rne(f1.x); a[5] = (short)bf16_rne(f1.y);
        a[6] = (short)bf16_rne(f1.z); a[7] = (short)bf16_rne(f1.w);
        afrag[kc] = a;
        if (mrow < NN) {
            uint4 st;
            st.x = pack2(f0.x * di, f0.y * di);
            st.y = pack2(f0.z * di, f0.w * di);
            st.z = pack2(f1.x * di, f1.y * di);
            st.w = pack2(f1.z * di, f1.w * di);
            *(uint4*)(featb_s + (size_t)mc * D + quad * 8 + kc * 32) = st;
        }
    }

    floatx4 acc[8];
    #pragma unroll
    for (int nt = 0; nt < 8; ++nt) acc[nt] = (floatx4)(0.0f);

    #pragma unroll
    for (int nt = 0; nt < 8; ++nt) {
        const unsigned short* brow = Wb + (size_t)(nt * 16 + r16) * D + quad * 8;
        #pragma unroll
        for (int kc = 0; kc < 4; ++kc) {
            const bf16x8 bfrag = *(const bf16x8*)(brow + kc * 32);
            acc[nt] = __builtin_amdgcn_mfma_f32_16x16x32_bf16(afrag[kc], bfrag, acc[nt], 0, 0, 0);
        }
    }

    // C/D layout: col=lane&15 (d), row=quad*4+reg (i)
    #pragma unroll
    for (int nt = 0; nt < 8; ++nt) {
        const int d = nt * 16 + r16;
        const float bd = b[d];
        #pragma unroll
        for (int r = 0; r < 4; ++r) {
            const int i = m0 + quad * 4 + r;
            if (i < NN) out[(size_t)i * D + d] = acc[nt][r] + bd;
        }
    }
}

// --------------------------------------------- shared gather inner loop
// acc[2l..2l+1] = sum_e rows[csr[e], 2l..2l+1]   (rows pre-scaled by dinv[src])
// 8x unroll; padded slots point at zero row NN.
__device__ __forceinline__ float2 gather_acc(const unsigned short* __restrict__ rows,
                                             const int* __restrict__ csr,
                                             int e0, int e1, int lane) {
    float2 acc = make_float2(0.0f, 0.0f);
    for (int bse = e0; bse < e1; bse += 64) {
        int idx = bse + lane;
        int s = (idx < e1) ? csr[idx] : NN;          // NN = zero dummy row
        int cnt8 = (min(64, e1 - bse) + 7) & ~7;
        for (int k = 0; k < cnt8; k += 8) {
            #pragma unroll
            for (int u = 0; u < 8; ++u) {            // 8 independent load chains
                int ss = __shfl(s, k + u);
                unsigned pv = *(const unsigned*)(rows + (size_t)ss * D + 2 * lane);
                acc.x += __uint_as_float(pv << 16);
                acc.y += __uint_as_float(pv & 0xFFFF0000u);
            }
        }
    }
    return acc;
}

// round 1: feat1s = bf16( (feat0 - acc*dinv_i*diag1) * dinv_i )
__global__ __launch_bounds__(256) void gather1_kernel(const unsigned short* __restrict__ featb_s,
                                                      const int* __restrict__ csr,
                                                      const int* __restrict__ row_ptr,
                                                      const float* __restrict__ dinvf,
                                                      const float* __restrict__ diag,
                                                      const float* __restrict__ feat0,
                                                      unsigned int* __restrict__ feat1s) {
    const int node = blockIdx.x * 4 + (threadIdx.x >> 6);
    const int lane = threadIdx.x & 63;
    float2 acc = gather_acc(featb_s, csr, row_ptr[node], row_ptr[node + 1], lane);

    const size_t o2 = (size_t)node * (D / 2) + lane;
    const float di = dinvf[node];
    const float2 bs = *(const float2*)&feat0[2 * o2];
    const float2 dg = *(const float2*)&diag[D + 2 * lane];
    float rx = bs.x - acc.x * di * dg.x;
    float ry = bs.y - acc.y * di * dg.y;
    feat1s[o2] = pack2(rx * di, ry * di);
}

// round 2: out += -0.5*(feat1 + acc*dinv_i*diag2),  feat1 = feat1s*rdeg_i
__global__ __launch_bounds__(256) void gather2_kernel(const unsigned short* __restrict__ feat1s,
                                                      const int* __restrict__ csr,
                                                      const int* __restrict__ row_ptr,
                                                      const float* __restrict__ dinvf,
                                                      const float* __restrict__ rdegf,
                                                      const float* __restrict__ diag,
                                                      float* __restrict__ outp) {
    const int node = blockIdx.x * 4 + (threadIdx.x >> 6);
    const int lane = threadIdx.x & 63;
    float2 acc = gather_acc(feat1s, csr, row_ptr[node], row_ptr[node + 1], lane);

    const size_t o2 = (size_t)node * (D / 2) + lane;
    const float di = dinvf[node];
    const float rd = rdegf[node];
    const unsigned bp = ((const unsigned*)feat1s)[o2];
    const float2 dg = *(const float2*)&diag[2 * D + 2 * lane];
    float bx = __uint_as_float(bp << 16) * rd;          // unscale
    float by = __uint_as_float(bp & 0xFFFF0000u) * rd;
    float2 cur = *(const float2*)&outp[2 * o2];
    cur.x -= 0.5f * (bx + acc.x * di * dg.x);
    cur.y -= 0.5f * (by + acc.y * di * dg.y);
    *(float2*)&outp[2 * o2] = cur;
}

// ----------------------------------------------------------------- launch
extern "C" void kernel_launch(void* const* d_in, const int* in_sizes, int n_in,
                              void* d_out, int out_size, void* d_ws, size_t ws_size,
                              hipStream_t stream) {
    const float* feat = (const float*)d_in[0];
    const int*   eidx = (const int*)d_in[1];
    const float* diag = (const float*)d_in[2];
    const float* W    = (const float*)d_in[3];
    const float* b    = (const float*)d_in[4];
    float* out = (float*)d_out;

    const int* src = eidx;            // edge_index[0]
    const int* dst = eidx + NE;       // edge_index[1]

    // ---- workspace layout (~28.3 MB) ----
    unsigned short* featb_s = (unsigned short*)d_ws;             // (NN+1)*D bf16
    unsigned short* feat1s  = featb_s + (size_t)(NN + 1) * D;    // (NN+1)*D bf16
    int*   csr      = (int*)(feat1s + (size_t)(NN + 1) * D);     // NE ints
    float* dinvf    = (float*)(csr + NE);                        // NN
    float* rdegf    = dinvf + NN;                                // NN
    int*   deg_i    = (int*)(rdegf + NN);                        // NN
    int*   row_ptr  = deg_i + NN;                                // NN+2
    int*   fillc    = row_ptr + NN + 2;                          // NN
    int*   partials = fillc + NN;                                // 256
    unsigned short* Wb = (unsigned short*)(partials + 256);      // 32 KB

    hipMemsetAsync(deg_i, 0, (size_t)NN * sizeof(int), stream);
    hipMemsetAsync(featb_s + (size_t)NN * D, 0, D * sizeof(unsigned short), stream); // zero row
    hipMemsetAsync(feat1s  + (size_t)NN * D, 0, D * sizeof(unsigned short), stream); // zero row

    hist_kernel<<<(NE + 255) / 256, 256, 0, stream>>>(dst, deg_i);
    scan1_kernel<<<NBLK, 256, 0, stream>>>(deg_i, row_ptr, partials, dinvf, rdegf);
    scan2_kernel<<<1, 256, 0, stream>>>(partials);
    scan3_kernel<<<NBLK, 256, 0, stream>>>(row_ptr, partials, fillc);
    fill_kernel<<<(NE + 255) / 256, 256, 0, stream>>>(src, dst, row_ptr, fillc, csr);

    wprep_kernel<<<64, 256, 0, stream>>>(W, diag, Wb);

    // out = h0 + b; featb_s = bf16(feat*dinv) byproduct
    gemm_mfma_kernel<<<(NN + 63) / 64, 256, 0, stream>>>(feat, Wb, b, dinvf, featb_s, out);

    // round 1: feat1s = bf16(feat1 * dinv)
    gather1_kernel<<<NN / 4, 256, 0, stream>>>(featb_s, csr, row_ptr, dinvf, diag,
                                               feat, (unsigned int*)feat1s);
    // round 2: out += -0.5*(feat1 + agg2*dinv*diag2)
    gather2_kernel<<<NN / 4, 256, 0, stream>>>(feat1s, csr, row_ptr, dinvf, rdegf, diag, out);
}